// Round 1
// baseline (231.552 us; speedup 1.0000x reference)
//
#include <hip/hip_runtime.h>
#include <math.h>

#define DIM 128
#define BATCH 8192
#define MARGIN 1.0f

__device__ __forceinline__ float wave_reduce_sum(float v) {
    // full 64-lane wave reduction; result valid in lane 0 (and replicated enough for our use)
    v += __shfl_down(v, 32, 64);
    v += __shfl_down(v, 16, 64);
    v += __shfl_down(v, 8, 64);
    v += __shfl_down(v, 4, 64);
    v += __shfl_down(v, 2, 64);
    v += __shfl_down(v, 1, 64);
    return v;
}

// One block (128 threads = 2 waves) per triple. Thread e owns output column e.
__global__ __launch_bounds__(128)
void transr_score_kernel(const int* __restrict__ pos_triples,
                         const int* __restrict__ neg_triples,
                         const float* __restrict__ entities,
                         const float* __restrict__ relations,
                         const float* __restrict__ transfer,
                         float* __restrict__ scores /* [2*BATCH] */) {
    const int b = blockIdx.x;               // 0 .. 2*BATCH-1
    const bool is_pos = (b < BATCH);
    const int i = is_pos ? b : (b - BATCH);
    const int* __restrict__ trip = is_pos ? pos_triples : neg_triples;

    const int h_idx = trip[i * 3 + 0];
    const int r_idx = trip[i * 3 + 1];
    const int t_idx = trip[i * 3 + 2];

    __shared__ float h_s[DIM];
    __shared__ float t_s[DIM];
    __shared__ float red_h[2], red_t[2], red_r[2], red_s[2];

    const int e = threadIdx.x;              // 0..127
    h_s[e] = entities[(size_t)h_idx * DIM + e];
    t_s[e] = entities[(size_t)t_idx * DIM + e];
    const float r_e = relations[(size_t)r_idx * DIM + e];
    __syncthreads();

    // h' [e] = sum_d h[d] * Mr[d][e] ;  t'[e] likewise. Mr row-major [d][e].
    const float* __restrict__ mr = transfer + (size_t)r_idx * (DIM * DIM) + e;
    float ah = 0.0f, at = 0.0f;
#pragma unroll 8
    for (int d = 0; d < DIM; ++d) {
        const float m = mr[(size_t)d * DIM];
        ah = fmaf(h_s[d], m, ah);
        at = fmaf(t_s[d], m, at);
    }

    // Block-reduce the three squared norms.
    const int lane = threadIdx.x & 63;
    const int w = threadIdx.x >> 6;
    float sh = wave_reduce_sum(ah * ah);
    float st = wave_reduce_sum(at * at);
    float sr = wave_reduce_sum(r_e * r_e);
    if (lane == 0) { red_h[w] = sh; red_t[w] = st; red_r[w] = sr; }
    __syncthreads();

    const float inh = 1.0f / fmaxf(sqrtf(red_h[0] + red_h[1]), 1e-12f);
    const float int_ = 1.0f / fmaxf(sqrtf(red_t[0] + red_t[1]), 1e-12f);
    const float inr = 1.0f / fmaxf(sqrtf(red_r[0] + red_r[1]), 1e-12f);

    const float val = ah * inh + r_e * inr - at * int_;
    float s = wave_reduce_sum(fabsf(val));
    if (lane == 0) red_s[w] = s;
    __syncthreads();

    if (threadIdx.x == 0) {
        scores[b] = red_s[0] + red_s[1];
    }
}

// Single block: mean(relu(pos - neg + margin)) over BATCH pairs.
__global__ __launch_bounds__(256)
void transr_loss_kernel(const float* __restrict__ scores, float* __restrict__ out) {
    float s = 0.0f;
    for (int i = threadIdx.x; i < BATCH; i += 256) {
        const float d = scores[i] - scores[BATCH + i] + MARGIN;
        s += (d > 0.0f) ? d : 0.0f;
    }
    s = wave_reduce_sum(s);
    __shared__ float red[4];
    const int lane = threadIdx.x & 63;
    const int w = threadIdx.x >> 6;
    if (lane == 0) red[w] = s;
    __syncthreads();
    if (threadIdx.x == 0) {
        out[0] = (red[0] + red[1] + red[2] + red[3]) * (1.0f / (float)BATCH);
    }
}

extern "C" void kernel_launch(void* const* d_in, const int* in_sizes, int n_in,
                              void* d_out, int out_size, void* d_ws, size_t ws_size,
                              hipStream_t stream) {
    const int*   pos       = (const int*)d_in[0];
    const int*   neg       = (const int*)d_in[1];
    const float* entities  = (const float*)d_in[2];
    const float* relations = (const float*)d_in[3];
    const float* transfer  = (const float*)d_in[4];
    float* out = (float*)d_out;

    float* scores = (float*)d_ws;   // 2*BATCH floats

    transr_score_kernel<<<2 * BATCH, 128, 0, stream>>>(
        pos, neg, entities, relations, transfer, scores);
    transr_loss_kernel<<<1, 256, 0, stream>>>(scores, out);
}

// Round 2
// 221.298 us; speedup vs baseline: 1.0463x; 1.0463x over previous
//
#include <hip/hip_runtime.h>
#include <math.h>

#define DIM 128
#define BATCH 8192
#define NTRIP (2 * BATCH)      // 16384
#define NREL 500
#define MARGIN 1.0f
#define TS 16                  // triples per tile
#define MAX_TILES 16           // covers up to 256 triples/relation (mean is 32.8)

__device__ __forceinline__ float wave_sum(float v) {
    // butterfly: result in all 64 lanes
    v += __shfl_xor(v, 32, 64);
    v += __shfl_xor(v, 16, 64);
    v += __shfl_xor(v, 8, 64);
    v += __shfl_xor(v, 4, 64);
    v += __shfl_xor(v, 2, 64);
    v += __shfl_xor(v, 1, 64);
    return v;
}

// ---- grouping pipeline -------------------------------------------------

__global__ __launch_bounds__(256)
void transr_count(const int* __restrict__ pos, const int* __restrict__ neg,
                  int* __restrict__ count) {
    const int i = blockIdx.x * 256 + threadIdx.x;   // 0..NTRIP-1
    if (i >= NTRIP) return;
    const int r = (i < BATCH) ? pos[i * 3 + 1] : neg[(i - BATCH) * 3 + 1];
    atomicAdd(&count[r], 1);
}

__global__ __launch_bounds__(512)
void transr_scan(const int* __restrict__ count, int* __restrict__ off,
                 int* __restrict__ cursor) {
    __shared__ int s[512];
    const int t = threadIdx.x;
    const int c = (t < NREL) ? count[t] : 0;
    s[t] = c;
    __syncthreads();
    for (int o = 1; o < 512; o <<= 1) {
        int v = s[t];
        if (t >= o) v += s[t - o];
        __syncthreads();
        s[t] = v;
        __syncthreads();
    }
    const int excl = s[t] - c;
    if (t <= NREL) off[t] = excl;        // off[NREL] == NTRIP
    if (t < NREL) cursor[t] = excl;
}

__global__ __launch_bounds__(256)
void transr_scatter(const int* __restrict__ pos, const int* __restrict__ neg,
                    int* __restrict__ cursor, int* __restrict__ sorted) {
    const int i = blockIdx.x * 256 + threadIdx.x;
    if (i >= NTRIP) return;
    const int r = (i < BATCH) ? pos[i * 3 + 1] : neg[(i - BATCH) * 3 + 1];
    const int slot = atomicAdd(&cursor[r], 1);
    sorted[slot] = i;
}

// ---- main scoring kernel ----------------------------------------------
// One block (128 threads = 2 waves) per (relation, tile of TS triples).
// Thread e owns output column e; Mr column element loaded once per tile,
// reused for 2*TS FMAs. h/t reads are block-uniform (scalar-load path).

__global__ __launch_bounds__(128)
void transr_main(const int* __restrict__ pos, const int* __restrict__ neg,
                 const float* __restrict__ entities,
                 const float* __restrict__ relations,
                 const float* __restrict__ transfer,
                 const int* __restrict__ rel_off, const int* __restrict__ sorted,
                 float* __restrict__ scores) {
    const int rel = blockIdx.x;
    const int tile = blockIdx.y;
    const int begin = rel_off[rel], end = rel_off[rel + 1];
    const int start = begin + tile * TS;
    if (start >= end) return;

    const int e = threadIdx.x;            // 0..127 (output column)
    const int lane = e & 63, w = e >> 6;

    __shared__ float redr[2];
    __shared__ float red[2][3 * TS];

    // r-hat (shared by every triple of this relation)
    const float r_e = relations[(size_t)rel * DIM + e];
    const float sr = wave_sum(r_e * r_e);
    if (lane == 0) redr[w] = sr;
    __syncthreads();
    const float rhat = r_e / fmaxf(sqrtf(redr[0] + redr[1]), 1e-12f);

    const float* __restrict__ mrcol = transfer + (size_t)rel * (DIM * DIM) + e;
    const bool last_tile = (tile == MAX_TILES - 1);

    for (int base = start; base < end; base += TS) {
        const int nk = min(TS, end - base);
        int ids[TS], hoff[TS], toff[TS];
        float acc_h[TS], acc_t[TS];

#pragma unroll
        for (int k = 0; k < TS; ++k) {
            int idx = base + k;
            idx = (idx < end) ? idx : (end - 1);   // clamp: recompute a valid triple
            const int id = sorted[idx];
            ids[k] = id;
            const int* trip = (id < BATCH) ? (pos + id * 3) : (neg + (id - BATCH) * 3);
            hoff[k] = trip[0] * DIM;
            toff[k] = trip[2] * DIM;
            acc_h[k] = 0.0f;
            acc_t[k] = 0.0f;
        }

#pragma unroll 2
        for (int d = 0; d < DIM; d += 4) {
            const float m0 = mrcol[(size_t)(d + 0) * DIM];
            const float m1 = mrcol[(size_t)(d + 1) * DIM];
            const float m2 = mrcol[(size_t)(d + 2) * DIM];
            const float m3 = mrcol[(size_t)(d + 3) * DIM];
#pragma unroll
            for (int k = 0; k < TS; ++k) {
                const float4 hv = *(const float4*)(entities + hoff[k] + d);
                const float4 tv = *(const float4*)(entities + toff[k] + d);
                acc_h[k] = fmaf(hv.w, m3, fmaf(hv.z, m2, fmaf(hv.y, m1, fmaf(hv.x, m0, acc_h[k]))));
                acc_t[k] = fmaf(tv.w, m3, fmaf(tv.z, m2, fmaf(tv.y, m1, fmaf(tv.x, m0, acc_t[k]))));
            }
        }

        // norms: block reduction over the 128 columns (2 waves)
#pragma unroll
        for (int k = 0; k < TS; ++k) {
            const float sh = wave_sum(acc_h[k] * acc_h[k]);
            const float st = wave_sum(acc_t[k] * acc_t[k]);
            if (lane == 0) { red[w][k] = sh; red[w][TS + k] = st; }
        }
        __syncthreads();
#pragma unroll
        for (int k = 0; k < TS; ++k) {
            const float inh = 1.0f / fmaxf(sqrtf(red[0][k] + red[1][k]), 1e-12f);
            const float itt = 1.0f / fmaxf(sqrtf(red[0][TS + k] + red[1][TS + k]), 1e-12f);
            const float val = fabsf(acc_h[k] * inh + rhat - acc_t[k] * itt);
            const float ss = wave_sum(val);
            if (lane == 0) red[w][2 * TS + k] = ss;
        }
        __syncthreads();
#pragma unroll
        for (int k = 0; k < TS; ++k) {
            if (k < nk && e == k) scores[ids[k]] = red[0][2 * TS + k] + red[1][2 * TS + k];
        }
        if (!last_tile) break;
        __syncthreads();   // protect red[] before next sub-tile (overflow path only)
    }
}

// ---- final loss reduction ---------------------------------------------

__global__ __launch_bounds__(512)
void transr_loss(const float* __restrict__ scores, float* __restrict__ out) {
    float s = 0.0f;
    for (int i = threadIdx.x; i < BATCH; i += 512) {
        const float d = scores[i] - scores[BATCH + i] + MARGIN;
        s += (d > 0.0f) ? d : 0.0f;
    }
    s = wave_sum(s);
    __shared__ float red[8];
    if ((threadIdx.x & 63) == 0) red[threadIdx.x >> 6] = s;
    __syncthreads();
    if (threadIdx.x == 0) {
        float t = 0.0f;
        for (int i = 0; i < 8; ++i) t += red[i];
        out[0] = t * (1.0f / (float)BATCH);
    }
}

extern "C" void kernel_launch(void* const* d_in, const int* in_sizes, int n_in,
                              void* d_out, int out_size, void* d_ws, size_t ws_size,
                              hipStream_t stream) {
    const int*   pos       = (const int*)d_in[0];
    const int*   neg       = (const int*)d_in[1];
    const float* entities  = (const float*)d_in[2];
    const float* relations = (const float*)d_in[3];
    const float* transfer  = (const float*)d_in[4];
    float* out = (float*)d_out;

    // workspace layout (ints/floats, 4B units)
    float* scores    = (float*)d_ws;                 // [0, 16384)
    int*   wsi       = (int*)d_ws;
    int*   rel_count = wsi + 16384;                  // [16384, 16896)
    int*   rel_off   = wsi + 16896;                  // [16896, 17408)
    int*   rel_cur   = wsi + 17408;                  // [17408, 17920)
    int*   sorted    = wsi + 17920;                  // [17920, 34304)

    hipMemsetAsync(rel_count, 0, 512 * sizeof(int), stream);
    transr_count<<<(NTRIP + 255) / 256, 256, 0, stream>>>(pos, neg, rel_count);
    transr_scan<<<1, 512, 0, stream>>>(rel_count, rel_off, rel_cur);
    transr_scatter<<<(NTRIP + 255) / 256, 256, 0, stream>>>(pos, neg, rel_cur, sorted);
    transr_main<<<dim3(NREL, MAX_TILES), 128, 0, stream>>>(
        pos, neg, entities, relations, transfer, rel_off, sorted, scores);
    transr_loss<<<1, 512, 0, stream>>>(scores, out);
}

// Round 3
// 153.390 us; speedup vs baseline: 1.5096x; 1.4427x over previous
//
#include <hip/hip_runtime.h>
#include <math.h>

#define DIM 128
#define BATCH 8192
#define NTRIP (2 * BATCH)      // 16384
#define NREL 500
#define MARGIN 1.0f
#define BSTR 136               // bf16 elements per LDS row of B^T (128 + 8 pad, 16B-aligned rows)

typedef __attribute__((ext_vector_type(8))) short short8;
typedef __attribute__((ext_vector_type(4))) float f32x4;

__device__ __forceinline__ float wave_sum(float v) {
    v += __shfl_xor(v, 32, 64);
    v += __shfl_xor(v, 16, 64);
    v += __shfl_xor(v, 8, 64);
    v += __shfl_xor(v, 4, 64);
    v += __shfl_xor(v, 2, 64);
    v += __shfl_xor(v, 1, 64);
    return v;
}

// exact fp32 -> bf16 round-to-nearest-even (finite values)
__device__ __forceinline__ short f2bf(float f) {
    unsigned u = __float_as_uint(f);
    u = (u + 0x7fffu + ((u >> 16) & 1u)) >> 16;
    return (short)u;
}

// ---- grouping: histogram + scan + scatter in ONE single-block kernel ----
__global__ __launch_bounds__(1024)
void transr_group(const int* __restrict__ pos, const int* __restrict__ neg,
                  int* __restrict__ rel_off, int* __restrict__ sorted,
                  int* __restrict__ done) {
    __shared__ int cnt[NREL];
    __shared__ int cur[NREL];
    __shared__ int s[512];
    const int tid = threadIdx.x;
    if (tid < NREL) cnt[tid] = 0;
    if (tid == 0) done[0] = 0;
    __syncthreads();
    for (int i = tid; i < NTRIP; i += 1024) {
        const int r = (i < BATCH) ? pos[i * 3 + 1] : neg[(i - BATCH) * 3 + 1];
        atomicAdd(&cnt[r], 1);
    }
    __syncthreads();
    if (tid < 512) s[tid] = (tid < NREL) ? cnt[tid] : 0;
    __syncthreads();
    for (int o = 1; o < 512; o <<= 1) {
        int v = 0;
        if (tid < 512) { v = s[tid]; if (tid >= o) v += s[tid - o]; }
        __syncthreads();
        if (tid < 512) s[tid] = v;
        __syncthreads();
    }
    if (tid < NREL) {
        const int excl = s[tid] - cnt[tid];
        cur[tid] = excl;
        rel_off[tid] = excl;
    }
    if (tid == 0) rel_off[NREL] = NTRIP;
    __syncthreads();
    for (int i = tid; i < NTRIP; i += 1024) {
        const int r = (i < BATCH) ? pos[i * 3 + 1] : neg[(i - BATCH) * 3 + 1];
        const int slot = atomicAdd(&cur[r], 1);
        sorted[slot] = i;
    }
}

// ---- main: one block per relation; bf16 MFMA; fused loss tail ----------
__global__ __launch_bounds__(256)
void transr_main(const int* __restrict__ pos, const int* __restrict__ neg,
                 const float* __restrict__ entities,
                 const float* __restrict__ relations,
                 const float* __restrict__ transfer,
                 const int* __restrict__ rel_off, const int* __restrict__ sorted,
                 float* __restrict__ scores, int* __restrict__ done,
                 float* __restrict__ out) {
    __shared__ __align__(16) short Bt[DIM * BSTR];   // B^T bf16: Bt[n][k]
    __shared__ float rhat[DIM];
    __shared__ float lred[8];
    __shared__ int lflag;

    const int rel = blockIdx.x;
    const int tid = threadIdx.x;
    const int begin = rel_off[rel], end = rel_off[rel + 1];
    const int cnt = end - begin;

    // stage Mr (fp32, row-major [k][n]) -> Bt (bf16, [n][k]), coalesced reads
    const float* __restrict__ mr = transfer + (size_t)rel * (DIM * DIM);
#pragma unroll
    for (int it = 0; it < 16; ++it) {
        const int idx = it * 256 + tid;            // float4 index, 4096 total
        const float4 v = ((const float4*)mr)[idx];
        const int k = (idx * 4) >> 7;              // source row (= K dim)
        const int n = (idx * 4) & 127;             // source col base
        Bt[(n + 0) * BSTR + k] = f2bf(v.x);
        Bt[(n + 1) * BSTR + k] = f2bf(v.y);
        Bt[(n + 2) * BSTR + k] = f2bf(v.z);
        Bt[(n + 3) * BSTR + k] = f2bf(v.w);
    }
    if (tid < DIM) rhat[tid] = relations[(size_t)rel * DIM + tid];
    __syncthreads();
    if (tid < 64) {
        const float a = rhat[tid], b = rhat[tid + 64];
        const float ss = wave_sum(a * a + b * b);
        if (tid == 0) lred[0] = 1.0f / fmaxf(sqrtf(ss), 1e-12f);
    }
    __syncthreads();
    const float rinv = lred[0];

    const int lane = tid & 63;
    const int w = tid >> 6;
    const int n = lane & 15;          // MFMA col / A-row id
    const int q = lane >> 4;          // quad

    float r_reg[8];
#pragma unroll
    for (int nt = 0; nt < 8; ++nt) r_reg[nt] = rhat[nt * 16 + n] * rinv;

    // A-row this lane feeds: rows 0-7 = h of triples 0..7, rows 8-15 = t
    const int jm = n & 7;
    const int sel = n >> 3;

    const int ntiles = (cnt + 7) >> 3;
    for (int tile = w; tile < ntiles; tile += 4) {
        int idxA = begin + tile * 8 + jm;
        if (idxA >= end) idxA = end - 1;
        const int idA = sorted[idxA];
        const int* trip = (idA < BATCH) ? (pos + idA * 3) : (neg + (idA - BATCH) * 3);
        const int ent = trip[sel ? 2 : 0];
        const float* __restrict__ erow = entities + (size_t)ent * DIM;

        short8 afrag[4];
#pragma unroll
        for (int kc = 0; kc < 4; ++kc) {
            const float4 u0 = *(const float4*)(erow + kc * 32 + q * 8);
            const float4 u1 = *(const float4*)(erow + kc * 32 + q * 8 + 4);
            short8 a;
            a[0] = f2bf(u0.x); a[1] = f2bf(u0.y); a[2] = f2bf(u0.z); a[3] = f2bf(u0.w);
            a[4] = f2bf(u1.x); a[5] = f2bf(u1.y); a[6] = f2bf(u1.z); a[7] = f2bf(u1.w);
            afrag[kc] = a;
        }

        f32x4 acc[8];
#pragma unroll
        for (int nt = 0; nt < 8; ++nt) acc[nt] = (f32x4){0.0f, 0.0f, 0.0f, 0.0f};
#pragma unroll
        for (int nt = 0; nt < 8; ++nt) {
            const int col = nt * 16 + n;
#pragma unroll
            for (int kc = 0; kc < 4; ++kc) {
                const short8 b = *(const short8*)(&Bt[col * BSTR + kc * 32 + q * 8]);
                acc[nt] = __builtin_amdgcn_mfma_f32_16x16x32_bf16(afrag[kc], b, acc[nt], 0, 0, 0);
            }
        }

        // epilogue: norms + |h^ + r^ - t^| sums, all in-wave
        float p[4];
#pragma unroll
        for (int reg = 0; reg < 4; ++reg) {
            float ss = 0.0f;
#pragma unroll
            for (int nt = 0; nt < 8; ++nt) { const float v = acc[nt][reg]; ss = fmaf(v, v, ss); }
            ss += __shfl_xor(ss, 1, 64);
            ss += __shfl_xor(ss, 2, 64);
            ss += __shfl_xor(ss, 4, 64);
            ss += __shfl_xor(ss, 8, 64);
            p[reg] = ss;     // norm^2 of C-row q*4+reg (h rows in quads 0-1, t rows in quads 2-3)
        }
#pragma unroll
        for (int reg = 0; reg < 4; ++reg) {
            const float pn = __shfl_xor(p[reg], 32, 64);           // partner (t) norm^2
            const float invh = 1.0f / fmaxf(sqrtf(p[reg]), 1e-12f);
            const float invt = 1.0f / fmaxf(sqrtf(pn), 1e-12f);
            float ss = 0.0f;
#pragma unroll
            for (int nt = 0; nt < 8; ++nt) {
                const float hv = acc[nt][reg];
                const float tv = __shfl_xor(acc[nt][reg], 32, 64); // t' same triple, same col
                ss += fabsf(fmaf(hv, invh, r_reg[nt]) - tv * invt);
            }
            ss += __shfl_xor(ss, 1, 64);
            ss += __shfl_xor(ss, 2, 64);
            ss += __shfl_xor(ss, 4, 64);
            ss += __shfl_xor(ss, 8, 64);
            if (q < 2 && n == 0) {
                int idxS = begin + tile * 8 + (q * 4 + reg);
                if (idxS >= end) idxS = end - 1;
                __hip_atomic_store(&scores[sorted[idxS]], ss,
                                   __ATOMIC_RELAXED, __HIP_MEMORY_SCOPE_AGENT);
            }
        }
    }

    // completion protocol + fused loss in the last block
    __syncthreads();
    if (tid == 0) {
        __threadfence();
        const int old = atomicAdd(done, 1);
        lflag = (old == NREL - 1) ? 1 : 0;
    }
    __syncthreads();
    if (lflag) {
        __threadfence();
        float ss = 0.0f;
        for (int i = tid; i < BATCH; i += 256) {
            const float a = __hip_atomic_load(&scores[i], __ATOMIC_RELAXED, __HIP_MEMORY_SCOPE_AGENT);
            const float b = __hip_atomic_load(&scores[BATCH + i], __ATOMIC_RELAXED, __HIP_MEMORY_SCOPE_AGENT);
            const float d = a - b + MARGIN;
            ss += (d > 0.0f) ? d : 0.0f;
        }
        ss = wave_sum(ss);
        if (lane == 0) lred[w] = ss;
        __syncthreads();
        if (tid == 0) out[0] = (lred[0] + lred[1] + lred[2] + lred[3]) * (1.0f / (float)BATCH);
    }
}

extern "C" void kernel_launch(void* const* d_in, const int* in_sizes, int n_in,
                              void* d_out, int out_size, void* d_ws, size_t ws_size,
                              hipStream_t stream) {
    const int*   pos       = (const int*)d_in[0];
    const int*   neg       = (const int*)d_in[1];
    const float* entities  = (const float*)d_in[2];
    const float* relations = (const float*)d_in[3];
    const float* transfer  = (const float*)d_in[4];
    float* out = (float*)d_out;

    // workspace layout (4B units)
    float* scores  = (float*)d_ws;        // [0, 16384)
    int*   wsi     = (int*)d_ws;
    int*   rel_off = wsi + 16384;         // [16384, 16885)
    int*   sorted  = wsi + 16896;         // [16896, 33280)
    int*   done    = wsi + 33280;         // [33280, 33281)

    transr_group<<<1, 1024, 0, stream>>>(pos, neg, rel_off, sorted, done);
    transr_main<<<NREL, 256, 0, stream>>>(pos, neg, entities, relations, transfer,
                                          rel_off, sorted, scores, done, out);
}